// Round 1
// baseline (80.207 us; speedup 1.0000x reference)
//
#include <hip/hip_runtime.h>

// Problem: N=2048, IN=32, SEG=16, OUT=64
// out[n,o] = sum_{i,s} mask * (slope*(xe-lo) + ylo), faithful to reference.
#define PN   2048
#define PIN  32
#define PSEG 16
#define POUT 64

#define NT   32   // n's covered per block
#define IC   4    // i's covered per block  (grid.y = PIN/IC = 8)
#define RPT  8    // n's per thread (NT / (256/64) = 32/4)

__global__ __launch_bounds__(256) void seg_kernel(
    const float* __restrict__ x_in,   // (N, IN)
    const float* __restrict__ xp,     // (IN, SEG+1, OUT)
    const float* __restrict__ yp,     // (IN, SEG+1, OUT)
    float* __restrict__ out)          // (N, OUT), pre-zeroed
{
    const int o     = threadIdx.x & 63;        // lane -> output column (coalesced)
    const int nrow  = threadIdx.x >> 6;        // 0..3
    const int nbase = (int)blockIdx.x * NT;    // 0..2047 step 32
    const int ibase = (int)blockIdx.y * IC;    // 0..31 step 4

    // Stage the x_in tile this block needs: NT x IC floats.
    __shared__ float xs[NT * IC];
    if (threadIdx.x < NT * IC) {
        const int n_l = threadIdx.x / IC;
        const int i_l = threadIdx.x % IC;
        xs[threadIdx.x] = x_in[(nbase + n_l) * PIN + (ibase + i_l)];
    }
    __syncthreads();

    float acc[RPT];
#pragma unroll
    for (int r = 0; r < RPT; ++r) acc[r] = 0.0f;

    for (int ii = 0; ii < IC; ++ii) {
        const int i = ibase + ii;
        const float* xpp = xp + (size_t)i * (PSEG + 1) * POUT + o;
        const float* ypp = yp + (size_t)i * (PSEG + 1) * POUT + o;

        float lo  = xpp[0];
        float ylo = ypp[0];

        float xe[RPT];
#pragma unroll
        for (int r = 0; r < RPT; ++r)
            xe[r] = xs[(nrow * RPT + r) * IC + ii];   // wave-uniform address: LDS broadcast

#pragma unroll
        for (int s = 0; s < PSEG; ++s) {
            const float hi  = xpp[(s + 1) * POUT];
            const float yhi = ypp[(s + 1) * POUT];
            float d = hi - lo;
            d = (d == 0.0f) ? 1e-4f : d;
            const float slope = (yhi - ylo) * __frcp_rn(d);
#pragma unroll
            for (int r = 0; r < RPT; ++r) {
                bool m = (xe[r] < hi) & (xe[r] >= lo);
                if (s == 0)        m = m | (xe[r] < lo);   // left-edge extension
                if (s == PSEG - 1) m = m | (xe[r] >= hi);  // right-edge extension
                const float val = fmaf(slope, xe[r] - lo, ylo);
                acc[r] += m ? val : 0.0f;
            }
            lo = hi; ylo = yhi;
        }
    }

#pragma unroll
    for (int r = 0; r < RPT; ++r) {
        const int n = nbase + nrow * RPT + r;
        atomicAdd(&out[(size_t)n * POUT + o], acc[r]);
    }
}

extern "C" void kernel_launch(void* const* d_in, const int* in_sizes, int n_in,
                              void* d_out, int out_size, void* d_ws, size_t ws_size,
                              hipStream_t stream)
{
    const float* x_in = (const float*)d_in[0];
    const float* xp   = (const float*)d_in[1];
    const float* yp   = (const float*)d_in[2];
    float* out        = (float*)d_out;

    // d_out is poisoned to 0xAA before every timed call; we accumulate with atomics.
    hipMemsetAsync(d_out, 0, (size_t)out_size * sizeof(float), stream);

    dim3 grid(PN / NT, PIN / IC);   // 64 x 8 = 512 blocks
    dim3 block(256);
    seg_kernel<<<grid, block, 0, stream>>>(x_in, xp, yp, out);
}